// Round 1
// baseline (222.282 us; speedup 1.0000x reference)
//
#include <hip/hip_runtime.h>
#include <stdint.h>

// Kill FMA contraction globally: label thresholds need bit-exact f32 IoU
// vs the numpy reference (a 1 vs -1 flip = error 2.0 > threshold 1.245).
#pragma clang fp contract(off)

#define NB 16       // batch
#define NA 12       // anchors per cell
#define NH 64
#define NW 64
#define NG 64       // gt boxes per batch
#define NN (NA*NH*NW)   // 49152 anchors per batch row
#define NBIN 4096   // rank histogram bins (top 12 of 23 rank bits)
#define CAP 1024    // boundary-bin list capacity per row (expected ~9)

// ws layout (uint32 index):
// [0] pos_cnt  [1] neg_cnt
// [2..18)  rowT (int32)   [18..34) rowBase   [34..50) listCnt
// [64 .. 64+16*4096)   hist
// [65600 .. 65600+16*CAP*2)  boundary lists (u, n) pairs
#define WS_HIST 64
#define WS_LIST 65600
#define WS_ZERO 65600   // zero [0, 65600)

__device__ __forceinline__ uint32_t rotl32(uint32_t x, int r) {
    return (x << r) | (x >> (32 - r));
}

// threefry2x32, key = jax.random.key(42) -> (0, 42), partitionable counters:
// x0 = hi(flat_idx)=0, x1 = lo(flat_idx)=i; 32-bit draw = out0 ^ out1.
__device__ uint32_t threefry_bits(uint32_t idx) {
    const uint32_t ks0 = 0u, ks1 = 42u, ks2 = 0x1BD11BDAu ^ 0u ^ 42u;
    uint32_t x0 = ks0;          // 0 + ks0
    uint32_t x1 = idx + ks1;
#define RND(r) { x0 += x1; x1 = rotl32(x1, r); x1 ^= x0; }
    RND(13) RND(15) RND(26) RND(6)
    x0 += ks1; x1 += ks2 + 1u;
    RND(17) RND(29) RND(16) RND(24)
    x0 += ks2; x1 += ks0 + 2u;
    RND(13) RND(15) RND(26) RND(6)
    x0 += ks0; x1 += ks1 + 3u;
    RND(17) RND(29) RND(16) RND(24)
    x0 += ks1; x1 += ks2 + 4u;
    RND(13) RND(15) RND(26) RND(6)
    x0 += ks2; x1 += ks0 + 5u;
#undef RND
    return x0 ^ x1;
}

__global__ __launch_bounds__(256) void k_zero(uint32_t* __restrict__ w) {
    int i = blockIdx.x * 256 + threadIdx.x;
    if (i < WS_ZERO) w[i] = 0u;
}

__global__ __launch_bounds__(256) void k_main(const float4* __restrict__ gt,
                                              const float4* __restrict__ anc,
                                              float* __restrict__ out,
                                              uint32_t* __restrict__ w) {
#pragma clang fp contract(off)
    const int b = blockIdx.y;
    const int n = blockIdx.x * 256 + threadIdx.x;
    const int t = threadIdx.x;

    __shared__ float sgx0[NG], sgy0[NG], sgx1[NG], sgy1[NG], sgar[NG];
    __shared__ float4 sg0[NG];   // batch-0 boxes (reference gt_flat indexing bug)
    if (t < NG) {
        float4 g = gt[b * NG + t];
        sgx0[t] = g.x; sgy0[t] = g.y;
        sgx1[t] = g.x + g.z;       // gx1 = x + w   (exact ref op order)
        sgy1[t] = g.y + g.w;
        sgar[t] = g.z * g.w;
    } else if (t < 2 * NG) {
        sg0[t - NG] = gt[t - NG];
    }
    __syncthreads();

    float4 a = anc[n];
    float ax1 = a.x + a.z;
    float ay1 = a.y + a.w;
    float aar = a.z * a.w;
    float kx1 = (a.x + a.z) - 1.0f;
    float ky1 = (a.y + a.w) - 1.0f;
    bool keep = (a.x >= 0.f) && (a.y >= 0.f) && (a.z >= 0.f) && (a.w >= 0.f)
             && (a.x <= 63.f) && (a.y <= 63.f) && (kx1 <= 63.f) && (ky1 <= 63.f);

    float best = -1.0f;   // all ov >= 1e-10 after zero-replacement
    int bi = 0;
    for (int g = 0; g < NG; ++g) {
        float iw = fminf(ax1, sgx1[g]) - fmaxf(a.x, sgx0[g]);
        iw = fmaxf(0.0f, iw);
        float ih = fminf(ay1, sgy1[g]) - fmaxf(a.y, sgy0[g]);
        ih = fmaxf(0.0f, ih);
        float inter = iw * ih;
        float uni = (aar + sgar[g]) - inter;
        float ov = inter / uni;
        if (ov == 0.0f) ov = 1e-10f;
        if (ov > best) { best = ov; bi = g; }   // first occurrence on ties
    }

    float label = -1.0f;
    if (keep) label = (best >= 0.7f) ? 1.0f : ((best <= 0.3f) ? 0.0f : -1.0f);

    if (keep && best > 0.7f) atomicAdd(&w[0], 1u);   // pos_cnt (strict >)
    if (keep && best < 0.3f) atomicAdd(&w[1], 1u);   // neg_cnt (strict <)

    float t0 = 0.f, t1 = 0.f, t2 = 0.f, t3 = 0.f;
    if (keep) {
        float4 g0 = sg0[bi];                  // always batch-0 (ref bug)
        t0 = a.x - g0.x / 16.0f;
        t1 = a.y - g0.y / 16.0f;
        t2 = a.z - g0.z / 16.0f;
        t3 = a.w - g0.w / 16.0f;
    }

    size_t base = ((size_t)b * NN + n) * 5;
    out[base + 0] = label;
    out[base + 1] = t0; out[base + 2] = t1;
    out[base + 3] = t2; out[base + 4] = t3;

    if (label == 0.0f) {
        uint32_t u = threefry_bits((uint32_t)(b * NN + n)) >> 9;  // 23-bit rank key
        atomicAdd(&w[WS_HIST + b * NBIN + (u >> 11)], 1u);
    }
}

__global__ __launch_bounds__(256) void k_scan(uint32_t* __restrict__ w) {
    const int b = blockIdx.x;
    const uint32_t* hist = w + WS_HIST + b * NBIN;
    __shared__ uint32_t csum[256];
    uint32_t pos = w[0];
    uint32_t cutoff = 3u * pos; if (cutoff < 1u) cutoff = 1u;
    int t = threadIdx.x;
    uint32_t s = 0;
    for (int k = 0; k < 16; ++k) s += hist[t * 16 + k];
    csum[t] = s;
    __syncthreads();
    if (t == 0) {
        uint32_t cum = 0; int tc = -1;
        for (int c = 255; c >= 0; --c) {
            if (cum + csum[c] >= cutoff) { tc = c; break; }
            cum += csum[c];
        }
        int T = -1; uint32_t base = 0;
        if (tc >= 0) {
            for (int k = 15; k >= 0; --k) {
                int bin = tc * 16 + k;
                uint32_t h = hist[bin];
                if (cum + h >= cutoff) { T = bin; base = cum; break; }
                cum += h;
            }
        }
        ((int32_t*)w)[2 + b] = T;   // -1: fewer than cutoff label-0 -> keep all
        w[18 + b] = base;           // exact ranks above bin T
        w[34 + b] = 0;              // boundary list count
    }
}

__global__ __launch_bounds__(256) void k_disable(float* __restrict__ out,
                                                 uint32_t* __restrict__ w) {
    const int b = blockIdx.y;
    const int n = blockIdx.x * 256 + threadIdx.x;
    uint32_t pos = w[0], neg = w[1];
    uint32_t cutoff = 3u * pos; if (cutoff < 1u) cutoff = 1u;
    if (neg <= cutoff) return;           // global gate
    int T = ((int32_t*)w)[2 + b];
    if (T < 0) return;
    size_t base = ((size_t)b * NN + n) * 5;
    if (out[base] != 0.0f) return;       // only label-0 anchors ranked
    uint32_t u = threefry_bits((uint32_t)(b * NN + n)) >> 9;
    int bin = (int)(u >> 11);
    if (bin > T) return;                 // rank < cutoff: stays 0
    if (bin < T) { out[base] = -1.0f; return; }   // rank >= cutoff: disabled
    uint32_t idx = atomicAdd(&w[34 + b], 1u);     // boundary bin: exact resolve
    if (idx < CAP) {
        uint32_t* lst = w + WS_LIST + ((size_t)b * CAP + idx) * 2;
        lst[0] = u; lst[1] = (uint32_t)n;
    }
}

__global__ __launch_bounds__(256) void k_resolve(float* __restrict__ out,
                                                 uint32_t* __restrict__ w) {
    const int b = blockIdx.x;
    uint32_t pos = w[0], neg = w[1];
    uint32_t cutoff = 3u * pos; if (cutoff < 1u) cutoff = 1u;
    if (neg <= cutoff) return;
    uint32_t cnt = w[34 + b]; if (cnt > CAP) cnt = CAP;
    uint32_t baseRank = w[18 + b];
    const uint32_t* lst = w + WS_LIST + (size_t)b * CAP * 2;
    for (uint32_t i = threadIdx.x; i < cnt; i += 256) {
        uint32_t u = lst[i * 2], n = lst[i * 2 + 1];
        uint32_t r = baseRank;
        for (uint32_t j = 0; j < cnt; ++j) {
            uint32_t uj = lst[j * 2], nj = lst[j * 2 + 1];
            // descending u, ties by smaller index first (stable argsort)
            r += (uj > u || (uj == u && nj < n)) ? 1u : 0u;
        }
        if (r >= cutoff) out[((size_t)b * NN + n) * 5] = -1.0f;
    }
}

extern "C" void kernel_launch(void* const* d_in, const int* in_sizes, int n_in,
                              void* d_out, int out_size, void* d_ws, size_t ws_size,
                              hipStream_t stream) {
    // d_in[0] = cls_scores (only shape-relevant, never read)
    const float4* gt  = (const float4*)d_in[1];
    const float4* anc = (const float4*)d_in[2];
    float* out = (float*)d_out;
    uint32_t* w = (uint32_t*)d_ws;

    k_zero<<<dim3((WS_ZERO + 255) / 256), 256, 0, stream>>>(w);
    k_main<<<dim3(NN / 256, NB), 256, 0, stream>>>(gt, anc, out, w);
    k_scan<<<dim3(NB), 256, 0, stream>>>(w);
    k_disable<<<dim3(NN / 256, NB), 256, 0, stream>>>(out, w);
    k_resolve<<<dim3(NB), 256, 0, stream>>>(out, w);
}